// Round 3
// baseline (158.227 us; speedup 1.0000x reference)
//
#include <hip/hip_runtime.h>

typedef __bf16 bf16x8 __attribute__((ext_vector_type(8)));
typedef float f32x4 __attribute__((ext_vector_type(4)));

#define TWO_LOG2E 2.88539008177792681f   // 2 * log2(e): exp(2*x) = exp2(x * TWO_LOG2E)

__device__ __forceinline__ unsigned short f2bf(float f) {
    unsigned int u = __float_as_uint(f);
    u = (u + 0x7FFFu + ((u >> 16) & 1u)) >> 16;   // RNE
    return (unsigned short)u;
}

// ---------------- kernel 1: row-normalize z=[z1;z2] -> bf16 zn[8192][256] ---------------
// Also zeroes S[8192] (blocks 0..31) and out[0] (block 32) so no memset dispatches needed.
__global__ void normalize_kernel(const float* __restrict__ z1,
                                 const float* __restrict__ z2,
                                 unsigned short* __restrict__ zn,
                                 float* __restrict__ S,
                                 float* __restrict__ out) {
    if (blockIdx.x < 32) S[(blockIdx.x << 8) + threadIdx.x] = 0.f;
    if (blockIdx.x == 32 && threadIdx.x == 0) out[0] = 0.f;

    const int wave = threadIdx.x >> 6, lane = threadIdx.x & 63;
    const int row = (blockIdx.x << 2) + wave;               // 2048 blocks * 4 rows
    const float* src = (row < 4096) ? (z1 + row * 256) : (z2 + (row - 4096) * 256);
    float4 v = ((const float4*)src)[lane];                  // 64 lanes * 4 = 256
    float ss = v.x * v.x + v.y * v.y + v.z * v.z + v.w * v.w;
#pragma unroll
    for (int m = 32; m > 0; m >>= 1) ss += __shfl_xor(ss, m, 64);
    float scale = 1.0f / fmaxf(sqrtf(ss), 1e-8f);
    uint2 w;
    w.x = (unsigned)f2bf(v.x * scale) | ((unsigned)f2bf(v.y * scale) << 16);
    w.y = (unsigned)f2bf(v.z * scale) | ((unsigned)f2bf(v.w * scale) << 16);
    *(uint2*)(zn + row * 256 + (lane << 2)) = w;
}

// ---------------- kernel 2: LDS-free, barrier-free triangular sim-exp ------------------
// One wave (64 threads) per block; each computes a 128x64 tile of sim via direct
// global->VGPR fragment loads (frag layout = 8 contiguous k elems/lane, so loads are
// 16B and coalesce into full 64B lines across the 4 quads). zn (4MB) is L2-resident.
// Triangular cover: row-tiles R of 128, col-tiles C of 64, keep C >= 2R (4160 tiles).
// Straddle tiles (C-2R < 2) predicate per element: j>=i -> row sum, j>i -> col sum.
__global__ void __launch_bounds__(64, 2) simexp_kernel(
    const unsigned short* __restrict__ zn,
    float* __restrict__ S)
{
    const int lane = threadIdx.x;
    const int q   = lane >> 4;          // quad
    const int n16 = lane & 15;

    // decode blockIdx -> (R, C) with C >= 2R
    int t = blockIdx.x, R = 0;
    while (t >= 128 - (R << 1)) { t -= 128 - (R << 1); ++R; }
    const int C = (R << 1) + t;
    const int rowBase = R << 7;         // 128 rows
    const int colBase = C << 6;         // 64 cols
    const bool straddle = (t < 2);

    // fragment base pointers: lane reads row (base + n16), k-offset q*8 (elements)
    const unsigned short* aptr = zn + ((rowBase + n16) << 8) + (q << 3);
    const unsigned short* bptr = zn + ((colBase + n16) << 8) + (q << 3);

    f32x4 acc[8][4];
#pragma unroll
    for (int i = 0; i < 8; ++i)
#pragma unroll
        for (int j = 0; j < 4; ++j) acc[i][j] = (f32x4){0.f, 0.f, 0.f, 0.f};

    bf16x8 a_frag[2][8], b_frag[2][4];
#pragma unroll
    for (int rt = 0; rt < 8; ++rt)                      // rt*16 rows = rt<<12 elems
        a_frag[0][rt] = *(const bf16x8*)(aptr + (rt << 12));
#pragma unroll
    for (int ct = 0; ct < 4; ++ct)
        b_frag[0][ct] = *(const bf16x8*)(bptr + (ct << 12));

#pragma unroll
    for (int s = 0; s < 8; ++s) {                       // K = 256 in k32 steps
        const int cur = s & 1, nxt = cur ^ 1;
        if (s < 7) {
            const int ko = (s + 1) << 5;                // next k-chunk (elements)
#pragma unroll
            for (int rt = 0; rt < 8; ++rt)
                a_frag[nxt][rt] = *(const bf16x8*)(aptr + (rt << 12) + ko);
#pragma unroll
            for (int ct = 0; ct < 4; ++ct)
                b_frag[nxt][ct] = *(const bf16x8*)(bptr + (ct << 12) + ko);
        }
#pragma unroll
        for (int rt = 0; rt < 8; ++rt)
#pragma unroll
            for (int ct = 0; ct < 4; ++ct)
                acc[rt][ct] = __builtin_amdgcn_mfma_f32_16x16x32_bf16(
                    a_frag[cur][rt], b_frag[cur][ct], acc[rt][ct], 0, 0, 0);
    }

    // epilogue: e = exp(2*dot); row sums (this tile) + col sums (transpose tile)
    float rs[8][4], cs[4];
#pragma unroll
    for (int i = 0; i < 8; ++i)
#pragma unroll
        for (int j = 0; j < 4; ++j) rs[i][j] = 0.f;
#pragma unroll
    for (int j = 0; j < 4; ++j) cs[j] = 0.f;

    const int ibase = rowBase + (q << 2);               // + rt*16 + r
    const int jbase = colBase + n16;                    // + ct*16
#pragma unroll
    for (int rt = 0; rt < 8; ++rt)
#pragma unroll
        for (int ct = 0; ct < 4; ++ct)
#pragma unroll
            for (int r = 0; r < 4; ++r) {
                float e = __builtin_amdgcn_exp2f(acc[rt][ct][r] * TWO_LOG2E);
                if (straddle) {
                    int i = ibase + (rt << 4) + r;
                    int j = jbase + (ct << 4);
                    rs[rt][r] += (j >= i) ? e : 0.f;    // diag counted once (row side)
                    cs[ct]    += (j >  i) ? e : 0.f;
                } else {
                    rs[rt][r] += e;
                    cs[ct]    += e;
                }
            }

    // row sums: reduce across 16 col-lanes (C/D: col=n16, row=q*4+r)
#pragma unroll
    for (int rt = 0; rt < 8; ++rt)
#pragma unroll
        for (int r = 0; r < 4; ++r) {
            float s = rs[rt][r];
            s += __shfl_xor(s, 1, 64);
            s += __shfl_xor(s, 2, 64);
            s += __shfl_xor(s, 4, 64);
            s += __shfl_xor(s, 8, 64);
            if (n16 == 0)
                atomicAdd(&S[rowBase + (rt << 4) + (q << 2) + r], s);
        }
    // col sums: reduce across the 4 quads (rows); lanes q==0 hold col n16 of group ct
#pragma unroll
    for (int ct = 0; ct < 4; ++ct) {
        float s = cs[ct];
        s += __shfl_xor(s, 16, 64);
        s += __shfl_xor(s, 32, 64);
        if (q == 0)
            atomicAdd(&S[colBase + (ct << 4) + n16], s);
    }
}

// ---------------- kernel 3: loss = mean( log(S_i - e^{sim_ii}) - sim_{i,target} ) -------
__global__ void finish_kernel(const unsigned short* __restrict__ zn,
                              const float* __restrict__ S,
                              float* __restrict__ out)
{
    __shared__ float vals[16];
    const int tid = threadIdx.x, lane = tid & 63, wave = tid >> 6;
    const int rib = (wave << 2) + (lane >> 4);      // 0..15 rows per block
    const int row = (blockIdx.x << 4) + rib;        // 512 blocks * 16 rows
    const int tar = (row + 4096) & 8191;
    const int l16 = lane & 15;

    float drr = 0.f, drt = 0.f;
#pragma unroll
    for (int i = 0; i < 4; ++i) {
        int k = (i << 6) + (l16 << 2);
        uint2 ur = *(const uint2*)(zn + (row << 8) + k);
        uint2 ut = *(const uint2*)(zn + (tar << 8) + k);
        float a0 = __uint_as_float(ur.x << 16);
        float a1 = __uint_as_float(ur.x & 0xFFFF0000u);
        float a2 = __uint_as_float(ur.y << 16);
        float a3 = __uint_as_float(ur.y & 0xFFFF0000u);
        float b0 = __uint_as_float(ut.x << 16);
        float b1 = __uint_as_float(ut.x & 0xFFFF0000u);
        float b2 = __uint_as_float(ut.y << 16);
        float b3 = __uint_as_float(ut.y & 0xFFFF0000u);
        drr += a0 * a0 + a1 * a1 + a2 * a2 + a3 * a3;
        drt += a0 * b0 + a1 * b1 + a2 * b2 + a3 * b3;
    }
#pragma unroll
    for (int m = 1; m <= 8; m <<= 1) {
        drr += __shfl_xor(drr, m, 64);
        drt += __shfl_xor(drt, m, 64);
    }
    if (l16 == 0) {
        float Sv = S[row] - __builtin_amdgcn_exp2f(drr * TWO_LOG2E);  // remove diagonal
        vals[rib] = 0.693147180559945f * __builtin_amdgcn_logf(Sv) - 2.0f * drt;
    }
    __syncthreads();
    if (tid == 0) {
        float s = 0.f;
#pragma unroll
        for (int i = 0; i < 16; ++i) s += vals[i];
        atomicAdd(out, s * (1.0f / 8192.0f));
    }
}

extern "C" void kernel_launch(void* const* d_in, const int* in_sizes, int n_in,
                              void* d_out, int out_size, void* d_ws, size_t ws_size,
                              hipStream_t stream)
{
    const float* z1 = (const float*)d_in[0];
    const float* z2 = (const float*)d_in[1];
    unsigned short* zn = (unsigned short*)d_ws;                       // 8192*256 bf16 = 4 MB
    float* S = (float*)((char*)d_ws + 8192 * 256 * sizeof(unsigned short)); // 32 KB
    float* out = (float*)d_out;

    normalize_kernel<<<2048, 256, 0, stream>>>(z1, z2, zn, S, out);
    simexp_kernel<<<4160, 64, 0, stream>>>(zn, S);
    finish_kernel<<<512, 256, 0, stream>>>(zn, S, out);
}